// Round 2
// baseline (206.791 us; speedup 1.0000x reference)
//
#include <hip/hip_runtime.h>
#include <math.h>

// B=128, IN=256, H=1024, L=256 -> 128 steps of (layerA, layerB). nA=512, nB=511.
#define NBATCH 128
#define NIN    256
#define NH     1024
#define NSTEPS 128
#define NA     512
#define NB     511

// Workspace layout (floats). Tables transposed: [layer][j(0..7)][lane(0..63)] float4
// {c0,s0,c1,s1}. tabB slot (j=7,lane=63)=pair 511 holds IDENTITY {1,0,1,0}.
#define TABA_OFF 0
#define TABB_OFF (NSTEPS * 512 * 4)
#define IHR_OFF  (TABB_OFF + NSTEPS * 512 * 4)
#define IHI_OFF  (IHR_OFF + NBATCH * NH)

#define GEMM_BLOCKS 128   // blocks [0,128): gemm.  [128,640): trig tables.
#define PREP_BLOCKS (GEMM_BLOCKS + 512)

// ---------------------------------------------------------------------------
// Kernel 1: fused {complex CLinear gemm} + {trig table build} (independent).
// ---------------------------------------------------------------------------
__global__ __launch_bounds__(256) void prep_kernel(
    const float* __restrict__ inR, const float* __restrict__ inI,
    const float* __restrict__ wR,  const float* __restrict__ wI,
    const float* __restrict__ biasR, const float* __restrict__ biasI,
    const float* __restrict__ A0, const float* __restrict__ A1,
    const float* __restrict__ B0, const float* __restrict__ B1,
    float* __restrict__ ws)
{
    __shared__ float xr_s[64][68], xi_s[64][68];
    __shared__ float wr_s[16][68], wi_s[16][68];

    if (blockIdx.x >= GEMM_BLOCKS) {
        // ---- trig branch: 512 blocks x 256 threads = 131072 = 65536A + 65408B + 128 id
        int idx = (blockIdx.x - GEMM_BLOCKS) * 256 + threadIdx.x;
        const int totalA = NSTEPS * NA;     // 65536
        const int totalB = NSTEPS * NB;     // 65408
        float4* tA = (float4*)(ws + TABA_OFF);
        float4* tB = (float4*)(ws + TABB_OFF);
        if (idx < totalA) {
            int l = idx >> 9, p = idx & 511;
            int lane = p >> 3, j = p & 7;
            float a0 = A0[idx], a1 = A1[idx];
            tA[l * 512 + j * 64 + lane] =
                make_float4(cosf(a0), sinf(a0), cosf(a1), sinf(a1));
        } else if (idx < totalA + totalB) {
            int q = idx - totalA;
            int l = q / NB, p = q - l * NB;
            int lane = p >> 3, j = p & 7;
            float b0 = B0[q], b1 = B1[q];
            tB[l * 512 + j * 64 + lane] =
                make_float4(cosf(b0), sinf(b0), cosf(b1), sinf(b1));
        } else {
            int l = idx - (totalA + totalB);          // 0..127
            tB[l * 512 + 511] = make_float4(1.f, 0.f, 1.f, 0.f);  // identity pad
        }
        return;
    }

    // ---- gemm branch: block = 16 h x 64 b, K staged in 4 tiles of 64.
    const int bid = blockIdx.x;
    const int h0 = (bid >> 1) * 16;
    const int b0 = (bid & 1) * 64;
    const int tid = threadIdx.x;
    const int hl = tid & 15, bg = tid >> 4;   // thread -> (h, 4 b's)

    float accR[4] = {0.f, 0.f, 0.f, 0.f};
    float accI[4] = {0.f, 0.f, 0.f, 0.f};

    for (int kt = 0; kt < 4; ++kt) {
        const int k0 = kt * 64;
        __syncthreads();
        // stage inputs: 64 rows x 16 float4 (coalesced)
        {
            int row = tid >> 4, col = tid & 15;
#pragma unroll
            for (int pass = 0; pass < 4; ++pass) {
                int r = pass * 16 + row;
                float4 vr = *(const float4*)(inR + (b0 + r) * NIN + k0 + col * 4);
                float4 vi = *(const float4*)(inI + (b0 + r) * NIN + k0 + col * 4);
                *(float4*)&xr_s[r][col * 4] = vr;
                *(float4*)&xi_s[r][col * 4] = vi;
            }
            float4 vr = *(const float4*)(wR + (h0 + row) * NIN + k0 + col * 4);
            float4 vi = *(const float4*)(wI + (h0 + row) * NIN + k0 + col * 4);
            *(float4*)&wr_s[row][col * 4] = vr;
            *(float4*)&wi_s[row][col * 4] = vi;
        }
        __syncthreads();
#pragma unroll 4
        for (int k4 = 0; k4 < 16; ++k4) {
            float4 wr = *(const float4*)&wr_s[hl][k4 * 4];
            float4 wi = *(const float4*)&wi_s[hl][k4 * 4];
#pragma unroll
            for (int j = 0; j < 4; ++j) {
                int bl = bg * 4 + j;
                float4 xr = *(const float4*)&xr_s[bl][k4 * 4];
                float4 xi = *(const float4*)&xi_s[bl][k4 * 4];
                accR[j] += xr.x * wr.x - xi.x * wi.x
                         + xr.y * wr.y - xi.y * wi.y
                         + xr.z * wr.z - xi.z * wi.z
                         + xr.w * wr.w - xi.w * wi.w;
                accI[j] += xr.x * wi.x + xi.x * wr.x
                         + xr.y * wi.y + xi.y * wr.y
                         + xr.z * wi.z + xi.z * wr.z
                         + xr.w * wi.w + xi.w * wr.w;
            }
        }
    }
    const float br = biasR[h0 + hl], bi = biasI[h0 + hl];
#pragma unroll
    for (int j = 0; j < 4; ++j) {
        int b = b0 + bg * 4 + j;
        ws[IHR_OFF + b * NH + h0 + hl] = accR[j] + br;
        ws[IHI_OFF + b * NH + h0 + hl] = accI[j] + bi;
    }
}

// ---------------------------------------------------------------------------
// Kernel 2: Clements mesh, ONE WAVE per batch row, 16 channels per lane.
// B-layer boundary exchange via shuffles -> zero barriers, zero LDS.
// ---------------------------------------------------------------------------
__global__ __launch_bounds__(64) void mesh_kernel(
    const float* __restrict__ stateR, const float* __restrict__ stateI,
    const float* __restrict__ omega,  const float* __restrict__ mod_bias,
    const float* __restrict__ ws, float* __restrict__ out)
{
    const int b = blockIdx.x;
    const int lane = threadIdx.x;
    const float4* tA = (const float4*)(ws + TABA_OFF);
    const float4* tB = (const float4*)(ws + TABB_OFF);

    float cr[16], ci[16];
    {
        const float4* sr4 = (const float4*)(stateR + b * NH + lane * 16);
        const float4* si4 = (const float4*)(stateI + b * NH + lane * 16);
#pragma unroll
        for (int q = 0; q < 4; ++q) {
            float4 r = sr4[q], i = si4[q];
            cr[4 * q] = r.x; cr[4 * q + 1] = r.y; cr[4 * q + 2] = r.z; cr[4 * q + 3] = r.w;
            ci[4 * q] = i.x; ci[4 * q + 1] = i.y; ci[4 * q + 2] = i.z; ci[4 * q + 3] = i.w;
        }
    }

    // left-boundary angle index: pair 8*lane-1 = (j=7, lane-1); lane 0 -> identity slot 511
    const int blIdx = (lane == 0) ? 511 : (447 + lane);

    float4 A[8], Bv[8], BL;
#pragma unroll
    for (int j = 0; j < 8; ++j) {
        A[j]  = tA[j * 64 + lane];
        Bv[j] = tB[j * 64 + lane];
    }
    BL = tB[blIdx];

    for (int l = 0; l < NSTEPS; ++l) {
        // prefetch next layer's angles (consumed after this iteration's compute)
        const int ln = (l < NSTEPS - 1) ? l + 1 : l;
        const int baseN = ln * 512;
        float4 nA[8], nB_[8], nBL;
#pragma unroll
        for (int j = 0; j < 8; ++j) {
            nA[j]  = tA[baseN + j * 64 + lane];
            nB_[j] = tB[baseN + j * 64 + lane];
        }
        nBL = tB[baseN + blIdx];

        // ---- layer A: pairs (c0,c1),(c2,c3),...  all register-local
#pragma unroll
        for (int j = 0; j < 8; ++j) {
            float ar = cr[2 * j], ai = ci[2 * j];
            float br = cr[2 * j + 1], bi = ci[2 * j + 1];
            float pr = A[j].x * ar - A[j].y * ai;
            float pi = A[j].y * ar + A[j].x * ai;
            cr[2 * j]     = A[j].z * pr - A[j].w * bi;
            ci[2 * j]     = A[j].z * pi + A[j].w * br;
            cr[2 * j + 1] = A[j].z * br - A[j].w * pi;
            ci[2 * j + 1] = A[j].z * bi + A[j].w * pr;
        }

        // ---- capture post-A boundary values from neighbors (no barrier needed)
        float rc0r  = __shfl_down(cr[0], 1, 64);
        float rc0i  = __shfl_down(ci[0], 1, 64);
        float lc15r = __shfl_up(cr[15], 1, 64);
        float lc15i = __shfl_up(ci[15], 1, 64);

        // ---- layer B local pairs (c1,c2),(c3,c4),...,(c13,c14)
#pragma unroll
        for (int j = 0; j < 7; ++j) {
            float ar = cr[2 * j + 1], ai = ci[2 * j + 1];
            float br = cr[2 * j + 2], bi = ci[2 * j + 2];
            float pr = Bv[j].x * ar - Bv[j].y * ai;
            float pi = Bv[j].y * ar + Bv[j].x * ai;
            cr[2 * j + 1] = Bv[j].z * pr - Bv[j].w * bi;
            ci[2 * j + 1] = Bv[j].z * pi + Bv[j].w * br;
            cr[2 * j + 2] = Bv[j].z * br - Bv[j].w * pi;
            ci[2 * j + 2] = Bv[j].z * bi + Bv[j].w * pr;
        }
        // ---- right boundary: my c15 (a-side) with right lane's c0 (b-side); a-output.
        //      lane 63 has identity angle -> passthrough, garbage shfl * 0.
        {
            float pr = Bv[7].x * cr[15] - Bv[7].y * ci[15];
            float pi = Bv[7].y * cr[15] + Bv[7].x * ci[15];
            cr[15] = Bv[7].z * pr - Bv[7].w * rc0i;
            ci[15] = Bv[7].z * pi + Bv[7].w * rc0r;
        }
        // ---- left boundary: left lane's c15 (a-side) with my c0 (b-side); b-output.
        //      lane 0 has identity angle -> passthrough.
        {
            float pr = BL.x * lc15r - BL.y * lc15i;
            float pi = BL.y * lc15r + BL.x * lc15i;
            float nr = BL.z * cr[0] - BL.w * pi;
            float ni = BL.z * ci[0] + BL.w * pr;
            cr[0] = nr; ci[0] = ni;
        }

#pragma unroll
        for (int j = 0; j < 8; ++j) { A[j] = nA[j]; Bv[j] = nB_[j]; }
        BL = nBL;
    }

    // ---- epilogue: diagonal phase, + ih, modReLU, store (2,B,H)
    const float4* ir4 = (const float4*)(ws + IHR_OFF + b * NH + lane * 16);
    const float4* ii4 = (const float4*)(ws + IHI_OFF + b * NH + lane * 16);
    const float4* om4 = (const float4*)(omega + lane * 16);
    const float4* mb4 = (const float4*)(mod_bias + lane * 16);
    float4* o0p = (float4*)(out + b * NH + lane * 16);
    float4* o1p = (float4*)(out + NBATCH * NH + b * NH + lane * 16);
#pragma unroll
    for (int q = 0; q < 4; ++q) {
        float4 ir = ir4[q], ii = ii4[q], om = om4[q], mb = mb4[q];
        float irs[4] = {ir.x, ir.y, ir.z, ir.w};
        float iis[4] = {ii.x, ii.y, ii.z, ii.w};
        float oms[4] = {om.x, om.y, om.z, om.w};
        float mbs[4] = {mb.x, mb.y, mb.z, mb.w};
        float o0[4], o1[4];
#pragma unroll
        for (int jj = 0; jj < 4; ++jj) {
            int j = q * 4 + jj;
            float co = cosf(oms[jj]), so = sinf(oms[jj]);
            float hhR = co * cr[j] - so * ci[j];
            float hhI = so * cr[j] + co * ci[j];
            float zr = irs[jj] + hhR;
            float zi = iis[jj] + hhI;
            float mag = sqrtf(zr * zr + zi * zi);
            float sc = fmaxf(mag + mbs[jj], 0.f) / fmaxf(mag, 1e-8f);
            o0[jj] = sc * zr;
            o1[jj] = sc * zi;
        }
        o0p[q] = make_float4(o0[0], o0[1], o0[2], o0[3]);
        o1p[q] = make_float4(o1[0], o1[1], o1[2], o1[3]);
    }
}

// ---------------------------------------------------------------------------
extern "C" void kernel_launch(void* const* d_in, const int* in_sizes, int n_in,
                              void* d_out, int out_size, void* d_ws, size_t ws_size,
                              hipStream_t stream)
{
    const float* inputsR = (const float*)d_in[0];
    const float* inputsI = (const float*)d_in[1];
    const float* stateR  = (const float*)d_in[2];
    const float* stateI  = (const float*)d_in[3];
    const float* weightR = (const float*)d_in[4];
    const float* weightI = (const float*)d_in[5];
    const float* biasR   = (const float*)d_in[6];
    const float* biasI   = (const float*)d_in[7];
    const float* angleA0 = (const float*)d_in[8];
    const float* angleA1 = (const float*)d_in[9];
    const float* angleB0 = (const float*)d_in[10];
    const float* angleB1 = (const float*)d_in[11];
    const float* omega   = (const float*)d_in[12];
    const float* mod_b   = (const float*)d_in[13];
    float* ws = (float*)d_ws;
    float* out = (float*)d_out;

    hipLaunchKernelGGL(prep_kernel, dim3(PREP_BLOCKS), dim3(256), 0, stream,
                       inputsR, inputsI, weightR, weightI, biasR, biasI,
                       angleA0, angleA1, angleB0, angleB1, ws);
    hipLaunchKernelGGL(mesh_kernel, dim3(NBATCH), dim3(64), 0, stream,
                       stateR, stateI, omega, mod_b, ws, out);
}

// Round 4
// 159.625 us; speedup vs baseline: 1.2955x; 1.2955x over previous
//
#include <hip/hip_runtime.h>
#include <math.h>

typedef float v2 __attribute__((ext_vector_type(2)));

// B=128, IN=256, H=1024 -> 128 steps of (layerA, layerB). nA=512, nB=511.
#define NBATCH 128
#define NIN    256
#define NH     1024
#define NSTEPS 128
#define NB     511

// Angle table: [layer][j(0..15)][lane(0..63)] float4 {c0,s0,c1,s1}
//   j 0..7  : A pair 8*lane+j
//   j 8..15 : B pair 8*lane+(j-8)   (slot (15,63)=pair 511 -> identity)
// Left-boundary angles (pair 8*lane-1) are obtained in-kernel by shuffling
// T[15] up one lane (lane 0 -> identity). Table = 2 MB; ih = 1 MB; total 3 MB
// (same ws footprint rounds 1-2 proved safe).
#define TAB_F4_PER_L 1024
#define IH_OFF (NSTEPS * TAB_F4_PER_L * 4)   // float offset; ih float4 = {R,I,R,I}

#define GEMM_BLOCKS 256
#define TRIG_BLOCKS 512                      // 512*256 = 128*1024 exactly

static __device__ __forceinline__ v2 to2(float a, float b) { v2 r; r.x = a; r.y = b; return r; }

// ---------------------------------------------------------------------------
// prep: blocks [0,256) complex gemm ih = in @ W^T + bias; [256,768) trig table
// ---------------------------------------------------------------------------
__global__ __launch_bounds__(256) void prep_kernel(
    const float* __restrict__ inR, const float* __restrict__ inI,
    const float* __restrict__ wR,  const float* __restrict__ wI,
    const float* __restrict__ biasR, const float* __restrict__ biasI,
    const float* __restrict__ A0, const float* __restrict__ A1,
    const float* __restrict__ B0, const float* __restrict__ B1,
    float* __restrict__ ws)
{
    __shared__ v2 xs[256][17];   // [k][b]  {xr,xi}
    __shared__ v2 wsh[32][34];   // [k][h]  {wr,wi}; stride 34 v2 = 272 B (16-aligned rows)

    if (blockIdx.x >= GEMM_BLOCKS) {
        // ---------------- trig branch ----------------
        int idx = (blockIdx.x - GEMM_BLOCKS) * 256 + threadIdx.x;
        int l = idx >> 10;
        int s = idx & 1023;
        int j = s >> 6, lane = s & 63;
        float a0, a1;
        bool ident = false;
        if (j < 8) {
            int p = 8 * lane + j;
            a0 = A0[l * 512 + p]; a1 = A1[l * 512 + p];
        } else {
            int p = 8 * lane + (j - 8);
            if (p < NB) { a0 = B0[l * NB + p]; a1 = B1[l * NB + p]; }
            else ident = true;
        }
        float4 v;
        if (ident) v = make_float4(1.f, 0.f, 1.f, 0.f);
        else {
            float s0, c0, s1, c1;
            __sincosf(a0, &s0, &c0);
            __sincosf(a1, &s1, &c1);
            v = make_float4(c0, s0, c1, s1);
        }
        ((float4*)ws)[l * TAB_F4_PER_L + j * 64 + lane] = v;
        return;
    }

    // ---------------- gemm branch: 32h x 16b tile ----------------
    const int ht = blockIdx.x >> 3, bt = blockIdx.x & 7;
    const int h0 = ht * 32, b0 = bt * 16;
    const int tid = threadIdx.x;

    // stage inputs for 16 batch rows: xs[k][b] = {inR, inI}
    {
        int b = tid >> 4, k4 = tid & 15;
#pragma unroll
        for (int p = 0; p < 4; ++p) {
            int k0 = p * 64 + k4 * 4;
            float4 vr = *(const float4*)(inR + (b0 + b) * NIN + k0);
            float4 vi = *(const float4*)(inI + (b0 + b) * NIN + k0);
            xs[k0 + 0][b] = to2(vr.x, vi.x);
            xs[k0 + 1][b] = to2(vr.y, vi.y);
            xs[k0 + 2][b] = to2(vr.z, vi.z);
            xs[k0 + 3][b] = to2(vr.w, vi.w);
        }
    }

    const int hg = tid & 15, bl = tid >> 4;   // thread: 2 h (h0+2hg, +1), 1 b
    v2 acc0 = to2(0.f, 0.f), acc1 = to2(0.f, 0.f);

    for (int c = 0; c < 8; ++c) {
        __syncthreads();
        // stage weight chunk: 32 h x 32 k as {wr,wi}
        {
            int hh = tid >> 3, k4 = tid & 7;
            float4 vr = *(const float4*)(wR + (h0 + hh) * NIN + c * 32 + k4 * 4);
            float4 vi = *(const float4*)(wI + (h0 + hh) * NIN + c * 32 + k4 * 4);
            wsh[k4 * 4 + 0][hh] = to2(vr.x, vi.x);
            wsh[k4 * 4 + 1][hh] = to2(vr.y, vi.y);
            wsh[k4 * 4 + 2][hh] = to2(vr.z, vi.z);
            wsh[k4 * 4 + 3][hh] = to2(vr.w, vi.w);
        }
        __syncthreads();
#pragma unroll
        for (int k = 0; k < 32; ++k) {
            float4 wv = *(const float4*)&wsh[k][hg * 2];   // {wr0,wi0,wr1,wi1}
            v2 w0 = to2(wv.x, wv.y), w1 = to2(wv.z, wv.w);
            v2 xv = xs[c * 32 + k][bl];
            acc0 += to2(xv.x, xv.x) * w0 + to2(xv.y, xv.y) * to2(-w0.y, w0.x);
            acc1 += to2(xv.x, xv.x) * w1 + to2(xv.y, xv.y) * to2(-w1.y, w1.x);
        }
    }
    int h = h0 + hg * 2, b = b0 + bl;
    acc0 += to2(biasR[h], biasI[h]);
    acc1 += to2(biasR[h + 1], biasI[h + 1]);
    ((float4*)(ws + IH_OFF))[b * 512 + (h >> 1)] =
        make_float4(acc0.x, acc0.y, acc1.x, acc1.y);
}

// ---------------------------------------------------------------------------
// mesh: one wave per batch row, 16 channels/lane, pk-fp32 MZIs, shuffle
// boundaries, explicit unroll-2 double-buffered angle prefetch.
// ---------------------------------------------------------------------------
__device__ __forceinline__ void mzi(const float4 t, v2& a, v2& b)
{
    // p = e^{i t0} a ; a' = c1 p + i s1 b ; b' = i s1 p + c1 b
    v2 P  = to2(t.x, t.y) * to2(a.x, a.x) + to2(-t.y, t.x) * to2(a.y, a.y);
    v2 na = to2(t.z, t.z) * P + to2(-t.w, t.w) * to2(b.y, b.x);
    b     = to2(t.z, t.z) * b + to2(-t.w, t.w) * to2(P.y, P.x);
    a = na;
}

__device__ __forceinline__ void step(v2* x, const float4* T, int lane)
{
    // A pairs 0 and 7 first so boundary shuffles issue early
    mzi(T[0], x[0], x[1]);
    mzi(T[7], x[14], x[15]);
    float rc0r  = __shfl_down(x[0].x, 1, 64);
    float rc0i  = __shfl_down(x[0].y, 1, 64);
    float lc15r = __shfl_up(x[15].x, 1, 64);
    float lc15i = __shfl_up(x[15].y, 1, 64);
    // left-boundary angles = left lane's T[15] (pair 8*lane-1); lane0 -> identity
    float blx = __shfl_up(T[15].x, 1, 64);
    float bly = __shfl_up(T[15].y, 1, 64);
    float blz = __shfl_up(T[15].z, 1, 64);
    float blw = __shfl_up(T[15].w, 1, 64);
    if (lane == 0) { blx = 1.f; bly = 0.f; blz = 1.f; blw = 0.f; }
#pragma unroll
    for (int j = 1; j < 7; ++j) mzi(T[j], x[2 * j], x[2 * j + 1]);
    // B local pairs
#pragma unroll
    for (int j = 0; j < 7; ++j) mzi(T[8 + j], x[2 * j + 1], x[2 * j + 2]);
    // right boundary: a-side update of x[15] with neighbor's post-A x[0]
    {
        const float4 t = T[15];
        v2 P = to2(t.x, t.y) * to2(x[15].x, x[15].x) + to2(-t.y, t.x) * to2(x[15].y, x[15].y);
        x[15] = to2(t.z, t.z) * P + to2(-t.w, t.w) * to2(rc0i, rc0r);
    }
    // left boundary: b-side update of x[0] with left's post-A x[15]
    {
        v2 P = to2(blx, bly) * to2(lc15r, lc15r) + to2(-bly, blx) * to2(lc15i, lc15i);
        x[0] = to2(blz, blz) * x[0] + to2(-blw, blw) * to2(P.y, P.x);
    }
}

#define LOADL(T, l)                                                       \
    do {                                                                  \
        const float4* _p = tab + (l) * TAB_F4_PER_L + lane;               \
        _Pragma("unroll") for (int _j = 0; _j < 16; ++_j)                 \
            T[_j] = _p[_j * 64];                                          \
    } while (0)

__global__ __launch_bounds__(64, 1) void mesh_kernel(
    const float* __restrict__ stateR, const float* __restrict__ stateI,
    const float* __restrict__ omega,  const float* __restrict__ mod_bias,
    const float* __restrict__ ws, float* __restrict__ out)
{
    const int b = blockIdx.x;
    const int lane = threadIdx.x;
    const float4* tab = (const float4*)ws;

    v2 x[16];
    {
        const float4* sr4 = (const float4*)(stateR + b * NH + lane * 16);
        const float4* si4 = (const float4*)(stateI + b * NH + lane * 16);
#pragma unroll
        for (int q = 0; q < 4; ++q) {
            float4 r = sr4[q], i = si4[q];
            x[4 * q + 0] = to2(r.x, i.x);
            x[4 * q + 1] = to2(r.y, i.y);
            x[4 * q + 2] = to2(r.z, i.z);
            x[4 * q + 3] = to2(r.w, i.w);
        }
    }

    float4 Ta[16], Tb[16];
    LOADL(Ta, 0);
    for (int l = 0; l < NSTEPS; l += 2) {
        LOADL(Tb, l + 1);
        __builtin_amdgcn_sched_barrier(0);
        step(x, Ta, lane);
        {
            int ln = (l + 2 < NSTEPS) ? l + 2 : NSTEPS - 1;
            LOADL(Ta, ln);
        }
        __builtin_amdgcn_sched_barrier(0);
        step(x, Tb, lane);
    }

    // epilogue: phase, + ih, modReLU
    float om[16], mb[16];
#pragma unroll
    for (int q = 0; q < 4; ++q) {
        float4 o = ((const float4*)(omega + lane * 16))[q];
        float4 m = ((const float4*)(mod_bias + lane * 16))[q];
        om[4 * q] = o.x; om[4 * q + 1] = o.y; om[4 * q + 2] = o.z; om[4 * q + 3] = o.w;
        mb[4 * q] = m.x; mb[4 * q + 1] = m.y; mb[4 * q + 2] = m.z; mb[4 * q + 3] = m.w;
    }
    float o0[16], o1[16];
    const float4* ihp = (const float4*)(ws + IH_OFF + b * NH * 2) + lane * 8;
#pragma unroll
    for (int q = 0; q < 8; ++q) {
        float4 ih2 = ihp[q];   // {R,I} for channels 2q, 2q+1
#pragma unroll
        for (int e = 0; e < 2; ++e) {
            int j = 2 * q + e;
            float ihr = (e == 0) ? ih2.x : ih2.z;
            float ihi = (e == 0) ? ih2.y : ih2.w;
            float so, co;
            __sincosf(om[j], &so, &co);
            float zr = ihr + co * x[j].x - so * x[j].y;
            float zi = ihi + so * x[j].x + co * x[j].y;
            float mag = sqrtf(zr * zr + zi * zi);
            float sc = fmaxf(mag + mb[j], 0.f) / fmaxf(mag, 1e-8f);
            o0[j] = sc * zr;
            o1[j] = sc * zi;
        }
    }
#pragma unroll
    for (int q = 0; q < 4; ++q) {
        ((float4*)(out + b * NH + lane * 16))[q] =
            make_float4(o0[4 * q], o0[4 * q + 1], o0[4 * q + 2], o0[4 * q + 3]);
        ((float4*)(out + NBATCH * NH + b * NH + lane * 16))[q] =
            make_float4(o1[4 * q], o1[4 * q + 1], o1[4 * q + 2], o1[4 * q + 3]);
    }
}

// ---------------------------------------------------------------------------
extern "C" void kernel_launch(void* const* d_in, const int* in_sizes, int n_in,
                              void* d_out, int out_size, void* d_ws, size_t ws_size,
                              hipStream_t stream)
{
    const float* inputsR = (const float*)d_in[0];
    const float* inputsI = (const float*)d_in[1];
    const float* stateR  = (const float*)d_in[2];
    const float* stateI  = (const float*)d_in[3];
    const float* weightR = (const float*)d_in[4];
    const float* weightI = (const float*)d_in[5];
    const float* biasR   = (const float*)d_in[6];
    const float* biasI   = (const float*)d_in[7];
    const float* angleA0 = (const float*)d_in[8];
    const float* angleA1 = (const float*)d_in[9];
    const float* angleB0 = (const float*)d_in[10];
    const float* angleB1 = (const float*)d_in[11];
    const float* omega   = (const float*)d_in[12];
    const float* mod_b   = (const float*)d_in[13];
    float* ws = (float*)d_ws;
    float* out = (float*)d_out;

    hipLaunchKernelGGL(prep_kernel, dim3(GEMM_BLOCKS + TRIG_BLOCKS), dim3(256),
                       0, stream, inputsR, inputsI, weightR, weightI,
                       biasR, biasI, angleA0, angleA1, angleB0, angleB1, ws);
    hipLaunchKernelGGL(mesh_kernel, dim3(NBATCH), dim3(64), 0, stream,
                       stateR, stateI, omega, mod_b, ws, out);
}